// Round 6
// baseline (3565.096 us; speedup 1.0000x reference)
//
#include <hip/hip_runtime.h>
#include <hip/hip_bf16.h>
#include <hip/hip_fp16.h>

#define NB 32      // batch
#define NS 256     // seq len
#define NI 1024    // input size
#define NO 1024    // hidden size
#define NK 2048    // NI + NO
#define NC 4096    // 4 * NO
#define LN_EPS 1e-5f

typedef __attribute__((ext_vector_type(4))) float f32x4;
typedef __attribute__((ext_vector_type(4))) unsigned int u32x4;
typedef __attribute__((ext_vector_type(8))) _Float16 f16x8;

__device__ __forceinline__ f32x4 mfma_bf16_16x16x32(u32x4 a, u32x4 b, f32x4 c) {
  asm volatile("v_mfma_f32_16x16x32_bf16 %0, %1, %2, %0" : "+v"(c) : "v"(a), "v"(b));
  return c;
}

__device__ __forceinline__ float sigf(float x) {
  return __builtin_amdgcn_rcpf(1.0f + __expf(-x));
}
// tanh(x) = 1 - 2/(e^{2x}+1); overflow -> 1, underflow -> -1. Both correct.
__device__ __forceinline__ float tanhfast(float x) {
  return 1.0f - 2.0f * __builtin_amdgcn_rcpf(__expf(2.0f * x) + 1.0f);
}

__device__ __forceinline__ unsigned short bf16u(float f) {
  union { float f; unsigned int u; } v; v.f = f;
  unsigned int r = (v.u + 0x7fff + ((v.u >> 16) & 1)) >> 16;  // RNE
  return (unsigned short)r;
}

// ---------------- setup kernels ----------------

// x fp32 [m][t][k] -> xfrag bf16 in MFMA A-fragment order (verified r4/r5).
__global__ void pack_x(const float* __restrict__ x, __hip_bfloat16* __restrict__ xfrag) {
  const int t = blockIdx.x, kt = blockIdx.y;
  const int tid = threadIdx.x;
  const int plane = tid >> 6, l = tid & 63, q = (l >> 4), ln = l & 15;
  const int m = plane * 16 + ln;
  const float* src = x + ((size_t)m * NS + t) * NI + kt * 32 + q * 8;
  float4 v0 = *(const float4*)src;
  float4 v1 = *(const float4*)(src + 4);
  __align__(16) __hip_bfloat16 tmp[8];
  tmp[0] = __float2bfloat16(v0.x); tmp[1] = __float2bfloat16(v0.y);
  tmp[2] = __float2bfloat16(v0.z); tmp[3] = __float2bfloat16(v0.w);
  tmp[4] = __float2bfloat16(v1.x); tmp[5] = __float2bfloat16(v1.y);
  tmp[6] = __float2bfloat16(v1.z); tmp[7] = __float2bfloat16(v1.w);
  *(u32x4*)(xfrag + (((size_t)t * 32 + kt) * 2 + plane) * 512 + l * 8) = *(const u32x4*)tmp;
}

// W fp32 [k=2048][n=4096] -> WF bf16 in MFMA-fragment order (verified r3-r5).
// Group b owns cols n(c) = (c>>2)*1024 + b*4 + (c&3).
__global__ void pack_wf(const float* __restrict__ W, __hip_bfloat16* __restrict__ WF) {
  const int blk = blockIdx.x;
  const int b = blk >> 6, kt = blk & 63;
  const int l = threadIdx.x, q = l >> 4, c = l & 15;
  const int n  = ((c >> 2) << 10) + b * 4 + (c & 3);
  const int k0 = kt * 32 + q * 8;
  __align__(16) __hip_bfloat16 tmp[8];
#pragma unroll
  for (int j = 0; j < 8; ++j)
    tmp[j] = __float2bfloat16(W[(size_t)(k0 + j) * NC + n]);
  *(u32x4*)(WF + ((size_t)(b * 64 + kt) * 64 + l) * 8) = *(const u32x4*)tmp;
}

// hfrag index for h[m][j] (A-fragment order, 2 planes of 16 rows) - tier 1 path.
__device__ __forceinline__ size_t hfrag_idx(int m, int j) {
  const int kt = j >> 5, q = (j >> 3) & 3, jj = j & 7;
  const int plane = m >> 4, l = q * 16 + (m & 15);
  return (((size_t)kt * 2 + plane) * 64 + l) * 8 + jj;
}

__global__ void init_state(const float* __restrict__ hx0, const float* __restrict__ cx0,
                           __hip_bfloat16* __restrict__ hfrag, float* __restrict__ cst,
                           float* __restrict__ hf, _Float16* __restrict__ cH0) {
  const int i = blockIdx.x * 256 + threadIdx.x;  // 32768 = NB*NO
  const int m = i >> 10, j = i & (NO - 1);
  const float hv = hx0[j];
  hfrag[hfrag_idx(m, j)] = __float2bfloat16(hv);
  hf[i]  = hv;
  cst[i] = cx0[j];
  cH0[i] = (_Float16)cx0[j];
}

// ---------------- one-shot GEMM: xw[t][m][n] = bias[n] + x_t @ Wx (r5) ----------------
__global__ __launch_bounds__(512)
void precompute_xw(const __hip_bfloat16* __restrict__ xfrag,
                   const __hip_bfloat16* __restrict__ WF,
                   const float* __restrict__ bias,
                   float* __restrict__ xw) {
  const int tq = blockIdx.x, nb = blockIdx.y;
  const int tid = threadIdx.x;
  const int w = tid >> 6, l = tid & 63, q = l >> 4, c = l & 15;
  const int tp = w >> 2, ng = w & 3;
  const int t0  = tq * 4 + tp * 2;
  const int bg0 = nb * 8 + ng * 2;

  float bias_g[2];
#pragma unroll
  for (int g = 0; g < 2; ++g)
    bias_g[g] = bias[((c >> 2) << 10) + (bg0 + g) * 4 + (c & 3)];

  f32x4 acc[2][2][2] = {};   // [tt][plane][g]
  asm volatile("s_nop 1" ::);
  for (int kt = 0; kt < 32; ++kt) {
    u32x4 a[2][2], bb[2];
#pragma unroll
    for (int tt = 0; tt < 2; ++tt)
#pragma unroll
      for (int p = 0; p < 2; ++p)
        a[tt][p] = *(const u32x4*)(xfrag +
            (((size_t)(t0 + tt) * 32 + kt) * 2 + p) * 512 + l * 8);
#pragma unroll
    for (int g = 0; g < 2; ++g)
      bb[g] = *(const u32x4*)(WF + (((size_t)(bg0 + g) * 64 + kt) * 64 + l) * 8);
#pragma unroll
    for (int tt = 0; tt < 2; ++tt)
#pragma unroll
      for (int p = 0; p < 2; ++p)
#pragma unroll
        for (int g = 0; g < 2; ++g)
          acc[tt][p][g] = mfma_bf16_16x16x32(a[tt][p], bb[g], acc[tt][p][g]);
  }
  asm volatile("s_nop 7\n\ts_nop 7" ::);
#pragma unroll
  for (int tt = 0; tt < 2; ++tt)
#pragma unroll
    for (int p = 0; p < 2; ++p)
#pragma unroll
      for (int g = 0; g < 2; ++g) {
        const int n = ((c >> 2) << 10) + (bg0 + g) * 4 + (c & 3);
#pragma unroll
        for (int r = 0; r < 4; ++r) {
          const int row = p * 16 + q * 4 + r;
          xw[((size_t)(t0 + tt) * 32 + row) * NC + n] = acc[tt][p][g][r] + bias_g[g];
        }
      }
}

// ---------------- fused per-step kernel (tier 2) ----------------
// grid 256 = 2 m-halves (mp) x 128 n-blocks (nb). 512 threads (8 waves).
// Block (mp, nb): owns rows [mp*16, mp*16+16) and j-cols [8nb, 8nb+8)
// (= WF groups 2nb, 2nb+1 = 32 n-cols across 4 gates).
// Phases: P0 stats of step t-1 (from partials) -> P1 redundant h-recompute of
// its 16 rows (reads comb_prev fp16 + c_prev fp16; writes hfrag to LDS; owner
// threads write out/c_new) -> P2 h-GEMM K=1024 (A from LDS, B=WF from L2) ->
// P3 reduce + xw + write comb_new fp16 + partial LN stats.
__global__ __launch_bounds__(512)
void fused_step(const _Float16* __restrict__ comb_prev,
                _Float16* __restrict__ comb_new,
                const _Float16* __restrict__ c_prev,
                _Float16* __restrict__ c_new,
                const float* __restrict__ part_prev,   // [32][128][2]
                float* __restrict__ part_new,
                const __hip_bfloat16* __restrict__ WF,
                const float* __restrict__ xw,
                const float* __restrict__ gamma,
                const float* __restrict__ beta,
                const float* __restrict__ hx0,
                float* __restrict__ out,
                int t) {
  // hfragL: A-fragments for this mp-half's 16 rows, K=1024 -> 32 ktiles,
  // 65 slots/ktile (pad; slot = 16B) to break 8-way write conflicts.
  __shared__ __align__(16) unsigned short hfragL[32 * 65 * 8];   // 33.3KB
  __shared__ __align__(16) float xchL[8][2][256];                // 16KB
  __shared__ float statL[16][2];

  const int mp = blockIdx.x & 1, nb = blockIdx.x >> 1;
  const int tid = threadIdx.x;

  if (t > 0) {
    // ---- P0: LN stats for step t-1 from per-block partials ----
    {
      const int row = tid >> 5, rr = tid & 31;
      const float* pp = part_prev + ((size_t)(mp * 16 + row) * 128 + rr * 4) * 2;
      f32x4 v1 = *(const f32x4*)pp;
      f32x4 v2 = *(const f32x4*)(pp + 4);
      float s  = v1[0] + v1[2] + v2[0] + v2[2];
      float ss = v1[1] + v1[3] + v2[1] + v2[3];
      s += __shfl_xor(s, 1);  ss += __shfl_xor(ss, 1);
      s += __shfl_xor(s, 2);  ss += __shfl_xor(ss, 2);
      s += __shfl_xor(s, 4);  ss += __shfl_xor(ss, 4);
      s += __shfl_xor(s, 8);  ss += __shfl_xor(ss, 8);
      s += __shfl_xor(s, 16); ss += __shfl_xor(ss, 16);
      if (rr == 0) {
        const float mean = s * (1.f / NC);
        const float var  = ss * (1.f / NC) - mean * mean;
        statL[row][0] = mean;
        statL[row][1] = rsqrtf(var + LN_EPS);
      }
    }
    __syncthreads();

    // ---- P1: recompute h_{t-1} for our 16 rows; build LDS A-fragments ----
    const int m16 = tid >> 5, r = tid & 31;
    const int m = mp * 16 + m16;
    const float mean = statL[m16][0], rstd = statL[m16][1];
#pragma unroll
    for (int i = 0; i < 4; ++i) {
      const int j0 = i * 256 + r * 8;
      float av[4][8];
#pragma unroll
      for (int g = 0; g < 4; ++g) {
        f16x8 cb = *(const f16x8*)(comb_prev + (size_t)m * NC + g * 1024 + j0);
        f32x4 ga = *(const f32x4*)(gamma + g * 1024 + j0);
        f32x4 gb = *(const f32x4*)(gamma + g * 1024 + j0 + 4);
        f32x4 ba = *(const f32x4*)(beta  + g * 1024 + j0);
        f32x4 bb = *(const f32x4*)(beta  + g * 1024 + j0 + 4);
#pragma unroll
        for (int jj = 0; jj < 4; ++jj) {
          av[g][jj]     = ((float)cb[jj]     - mean) * rstd * ga[jj] + ba[jj];
          av[g][jj + 4] = ((float)cb[jj + 4] - mean) * rstd * gb[jj] + bb[jj];
        }
      }
      f16x8 c8 = *(const f16x8*)(c_prev + (size_t)m * NO + j0);
      __align__(16) unsigned short hb[8];
      _Float16 cn8[8];
      float hf_[8];
#pragma unroll
      for (int jj = 0; jj < 8; ++jj) {
        const float cn = sigf(av[1][jj]) * (float)c8[jj] + sigf(av[0][jj]) * tanhfast(av[2][jj]);
        const float hh = sigf(av[3][jj]) * cn;
        cn8[jj] = (_Float16)cn;
        hf_[jj] = hh;
        hb[jj]  = bf16u(hh);
      }
      // A-fragment slot: kt = j0>>5 = i*8+(r>>2), q = r&3
      const int slot = (i * 8 + (r >> 2)) * 65 + (r & 3) * 16 + m16;
      *(u32x4*)(hfragL + (size_t)slot * 8) = *(const u32x4*)hb;
      if ((i * 32 + r) == nb) {   // owner of j-cols [8nb, 8nb+8)
        float* op = out + ((size_t)m * NS + (t - 1)) * NO + j0;
#pragma unroll
        for (int jj = 0; jj < 8; ++jj) op[jj] = hf_[jj];
        *(u32x4*)(c_new + (size_t)m * NO + j0) = *(const u32x4*)cn8;
      }
    }
  } else {
    // ---- t == 0: A-fragments from broadcast init h ----
    const int m16 = tid >> 5, r = tid & 31;
#pragma unroll
    for (int i = 0; i < 4; ++i) {
      const int j0 = i * 256 + r * 8;
      f32x4 v0 = *(const f32x4*)(hx0 + j0);
      f32x4 v1 = *(const f32x4*)(hx0 + j0 + 4);
      __align__(16) unsigned short hb[8];
#pragma unroll
      for (int jj = 0; jj < 4; ++jj) { hb[jj] = bf16u(v0[jj]); hb[jj + 4] = bf16u(v1[jj]); }
      const int slot = (i * 8 + (r >> 2)) * 65 + (r & 3) * 16 + m16;
      *(u32x4*)(hfragL + (size_t)slot * 8) = *(const u32x4*)hb;
    }
  }
  __syncthreads();

  // ---- P2: h-GEMM, K=1024. Wave w covers ktiles [w*4, w*4+4). ----
  {
    const int w = tid >> 6, l = tid & 63;
    f32x4 acc0 = {0.f, 0.f, 0.f, 0.f}, acc1 = {0.f, 0.f, 0.f, 0.f};
    asm volatile("s_nop 1" ::);
#pragma unroll
    for (int i = 0; i < 4; ++i) {
      const int kt = w * 4 + i;
      u32x4 a  = *(const u32x4*)(hfragL + ((size_t)kt * 65 + l) * 8);
      u32x4 b0 = *(const u32x4*)(WF + (((size_t)(2 * nb + 0) * 64 + 32 + kt) * 64 + l) * 8);
      u32x4 b1 = *(const u32x4*)(WF + (((size_t)(2 * nb + 1) * 64 + 32 + kt) * 64 + l) * 8);
      acc0 = mfma_bf16_16x16x32(a, b0, acc0);
      acc1 = mfma_bf16_16x16x32(a, b1, acc1);
    }
    asm volatile("s_nop 7\n\ts_nop 7" ::);
    *(f32x4*)(&xchL[w][0][l * 4]) = acc0;
    *(f32x4*)(&xchL[w][1][l * 4]) = acc1;
  }
  __syncthreads();

  // ---- P3: reduce K-partials, add xw, write comb_new fp16 + LN partials ----
  {
    const int row = tid >> 5, nc = tid & 31;
    const int g = nc >> 4, c = nc & 15;
    const int idx = ((row >> 2) * 16 + c) * 4 + (row & 3);
    const int n = ((c >> 2) << 10) + (2 * nb + g) * 4 + (c & 3);
    const int m = mp * 16 + row;
    float v = xw[((size_t)t * 32 + m) * NC + n];   // bias folded in
#pragma unroll
    for (int w = 0; w < 8; ++w) v += xchL[w][g][idx];
    comb_new[(size_t)m * NC + n] = (_Float16)v;
    float s = v, ss = v * v;
    s += __shfl_xor(s, 1);  ss += __shfl_xor(ss, 1);
    s += __shfl_xor(s, 2);  ss += __shfl_xor(ss, 2);
    s += __shfl_xor(s, 4);  ss += __shfl_xor(ss, 4);
    s += __shfl_xor(s, 8);  ss += __shfl_xor(ss, 8);
    s += __shfl_xor(s, 16); ss += __shfl_xor(ss, 16);
    if (nc == 0) {
      float* pp = part_new + ((size_t)m * 128 + nb) * 2;
      pp[0] = s; pp[1] = ss;
    }
  }
}

// ---------------- final update: out[:, 255, :] ----------------
__global__ __launch_bounds__(1024)
void final_update(const _Float16* __restrict__ comb,   // comb_255
                  const _Float16* __restrict__ cprev,  // c_254
                  const float* __restrict__ part,
                  const float* __restrict__ gamma,
                  const float* __restrict__ beta,
                  float* __restrict__ out) {
  __shared__ float wsum[2][2];
  __shared__ float stat[2];
  const int m = blockIdx.x, tid = threadIdx.x;
  if (tid < 128) {
    const float* pp = part + ((size_t)m * 128 + tid) * 2;
    float s = pp[0], ss = pp[1];
    s += __shfl_xor(s, 1);  ss += __shfl_xor(ss, 1);
    s += __shfl_xor(s, 2);  ss += __shfl_xor(ss, 2);
    s += __shfl_xor(s, 4);  ss += __shfl_xor(ss, 4);
    s += __shfl_xor(s, 8);  ss += __shfl_xor(ss, 8);
    s += __shfl_xor(s, 16); ss += __shfl_xor(ss, 16);
    s += __shfl_xor(s, 32); ss += __shfl_xor(ss, 32);
    if ((tid & 63) == 0) { wsum[tid >> 6][0] = s; wsum[tid >> 6][1] = ss; }
  }
  __syncthreads();
  if (tid == 0) {
    const float s = wsum[0][0] + wsum[1][0], ss = wsum[0][1] + wsum[1][1];
    const float mean = s * (1.f / NC);
    const float var  = ss * (1.f / NC) - mean * mean;
    stat[0] = mean;
    stat[1] = rsqrtf(var + LN_EPS);
  }
  __syncthreads();
  const float mean = stat[0], rstd = stat[1];
  const int j = tid;
  const float iv = ((float)comb[(size_t)m * NC + j]          - mean) * rstd * gamma[j]          + beta[j];
  const float fv = ((float)comb[(size_t)m * NC + NO + j]     - mean) * rstd * gamma[NO + j]     + beta[NO + j];
  const float gv = ((float)comb[(size_t)m * NC + 2 * NO + j] - mean) * rstd * gamma[2 * NO + j] + beta[2 * NO + j];
  const float ov = ((float)comb[(size_t)m * NC + 3 * NO + j] - mean) * rstd * gamma[3 * NO + j] + beta[3 * NO + j];
  const float cn = sigf(fv) * (float)cprev[(size_t)m * NO + j] + sigf(iv) * tanhfast(gv);
  out[((size_t)m * NS + (NS - 1)) * NO + j] = sigf(ov) * cn;
}

// ---------------- tier-1 per-step kernels (round-4 proven path) ----------------

__global__ __launch_bounds__(512)
void step_gemm_mfma(const __hip_bfloat16* __restrict__ xfrag,
                    const __hip_bfloat16* __restrict__ hfrag,
                    const __hip_bfloat16* __restrict__ WF,
                    const float* __restrict__ bias,
                    float* __restrict__ comb, int t) {
  __shared__ __align__(16) float xch[8 * 2 * 256];
  const int b = blockIdx.x, tid = threadIdx.x;
  const int wv = tid >> 6, l = tid & 63;
  const __hip_bfloat16* ap = (wv < 4)
      ? xfrag + ((size_t)t * 32 + wv * 8) * 1024 + l * 8
      : hfrag + ((size_t)(wv - 4) * 8) * 1024 + l * 8;
  const __hip_bfloat16* bp = WF + ((size_t)(b * 64 + wv * 8) * 64 + l) * 8;
  f32x4 acc0 = {0.f, 0.f, 0.f, 0.f}, acc1 = {0.f, 0.f, 0.f, 0.f};
  asm volatile("s_nop 1" ::);
#pragma unroll
  for (int i = 0; i < 8; ++i) {
    u32x4 a0 = *(const u32x4*)(ap + (size_t)i * 1024);
    u32x4 a1 = *(const u32x4*)(ap + (size_t)i * 1024 + 512);
    u32x4 bb = *(const u32x4*)(bp + (size_t)i * 512);
    acc0 = mfma_bf16_16x16x32(a0, bb, acc0);
    acc1 = mfma_bf16_16x16x32(a1, bb, acc1);
  }
  asm volatile("s_nop 7\n\ts_nop 7" ::);
  *(f32x4*)(xch + (wv * 2 + 0) * 256 + l * 4) = acc0;
  *(f32x4*)(xch + (wv * 2 + 1) * 256 + l * 4) = acc1;
  __syncthreads();
  const int row = tid >> 4, c = tid & 15;
  const int p = row >> 4, rr = row & 15;
  const int idx = ((rr >> 2) * 16 + c) * 4 + (rr & 3);
  const int n = ((c >> 2) << 10) + b * 4 + (c & 3);
  float v = bias[n];
#pragma unroll
  for (int w = 0; w < 8; ++w) v += xch[(w * 2 + p) * 256 + idx];
  comb[(size_t)row * NC + n] = v;
}

__global__ __launch_bounds__(1024)
void step_update_row(const float* __restrict__ comb,
                     const float* __restrict__ gamma,
                     const float* __restrict__ beta,
                     float* __restrict__ cst,
                     float* __restrict__ out,
                     __hip_bfloat16* __restrict__ hfrag,
                     int t) {
  __shared__ __align__(16) float combL[NC];
  __shared__ float red[16][2];
  __shared__ float stat[2];
  const int m = blockIdx.x, tid = threadIdx.x;
  f32x4 cv = *(const f32x4*)(comb + (size_t)m * NC + tid * 4);
  *(f32x4*)(combL + tid * 4) = cv;
  float s  = cv[0] + cv[1] + cv[2] + cv[3];
  float ss = cv[0] * cv[0] + cv[1] * cv[1] + cv[2] * cv[2] + cv[3] * cv[3];
#pragma unroll
  for (int off = 1; off < 64; off <<= 1) {
    s  += __shfl_xor(s, off);
    ss += __shfl_xor(ss, off);
  }
  const int wid = tid >> 6;
  if ((tid & 63) == 0) { red[wid][0] = s; red[wid][1] = ss; }
  __syncthreads();
  if (tid == 0) {
    float s2 = 0.f, ss2 = 0.f;
#pragma unroll
    for (int i = 0; i < 16; ++i) { s2 += red[i][0]; ss2 += red[i][1]; }
    const float mean = s2 * (1.f / NC);
    const float var  = ss2 * (1.f / NC) - mean * mean;
    stat[0] = mean;
    stat[1] = rsqrtf(var + LN_EPS);
  }
  __syncthreads();
  const float mean = stat[0], rs = stat[1];
  const int j = tid;
  const float iv = (combL[j]          - mean) * rs * gamma[j]          + beta[j];
  const float fv = (combL[NO + j]     - mean) * rs * gamma[NO + j]     + beta[NO + j];
  const float gv = (combL[2 * NO + j] - mean) * rs * gamma[2 * NO + j] + beta[2 * NO + j];
  const float ov = (combL[3 * NO + j] - mean) * rs * gamma[3 * NO + j] + beta[3 * NO + j];
  const float cold = cst[(size_t)m * NO + j];
  const float cc = sigf(fv) * cold + sigf(iv) * tanhfast(gv);
  const float hh = sigf(ov) * cc;
  cst[(size_t)m * NO + j] = cc;
  out[((size_t)m * NS + t) * NO + j] = hh;
  hfrag[hfrag_idx(m, j)] = __float2bfloat16(hh);
}

// ---------------- tier-0 fp32 path ----------------

__launch_bounds__(256)
__global__ void step_gemm_f32(const float* __restrict__ x, const float* __restrict__ hf,
                              const float* __restrict__ W, const float* __restrict__ bias,
                              float* __restrict__ comb, int t) {
  const int blk = blockIdx.x;
  const int tid = threadIdx.x;
  const int n   = blk * 16 + (tid & 15);
  const int mlo = tid >> 4;
  float a0 = 0.f, a1 = 0.f;
  for (int k = 0; k < NI; ++k) {
    const float wv = W[(size_t)k * NC + n];
    a0 += x[((size_t)mlo * NS + t) * NI + k] * wv;
    a1 += x[((size_t)(mlo + 16) * NS + t) * NI + k] * wv;
  }
  for (int k = 0; k < NO; ++k) {
    const float wv = W[(size_t)(NI + k) * NC + n];
    a0 += hf[mlo * NO + k] * wv;
    a1 += hf[(mlo + 16) * NO + k] * wv;
  }
  comb[(size_t)mlo * NC + n] = a0 + bias[n];
  comb[(size_t)(mlo + 16) * NC + n] = a1 + bias[n];
}

__global__ __launch_bounds__(1024)
void step_update_row_f32(const float* __restrict__ comb,
                         const float* __restrict__ gamma,
                         const float* __restrict__ beta,
                         float* __restrict__ cst,
                         float* __restrict__ out,
                         float* __restrict__ hf,
                         int t) {
  __shared__ __align__(16) float combL[NC];
  __shared__ float red[16][2];
  __shared__ float stat[2];
  const int m = blockIdx.x, tid = threadIdx.x;
  f32x4 cv = *(const f32x4*)(comb + (size_t)m * NC + tid * 4);
  *(f32x4*)(combL + tid * 4) = cv;
  float s  = cv[0] + cv[1] + cv[2] + cv[3];
  float ss = cv[0] * cv[0] + cv[1] * cv[1] + cv[2] * cv[2] + cv[3] * cv[3];
#pragma unroll
  for (int off = 1; off < 64; off <<= 1) {
    s  += __shfl_xor(s, off);
    ss += __shfl_xor(ss, off);
  }
  const int wid = tid >> 6;
  if ((tid & 63) == 0) { red[wid][0] = s; red[wid][1] = ss; }
  __syncthreads();
  if (tid == 0) {
    float s2 = 0.f, ss2 = 0.f;
    for (int i = 0; i < 16; ++i) { s2 += red[i][0]; ss2 += red[i][1]; }
    const float mean = s2 * (1.f / NC);
    const float var  = ss2 * (1.f / NC) - mean * mean;
    stat[0] = mean;
    stat[1] = rsqrtf(var + LN_EPS);
  }
  __syncthreads();
  const float mean = stat[0], rs = stat[1];
  const int j = tid;
  const float iv = (combL[j]          - mean) * rs * gamma[j]          + beta[j];
  const float fv = (combL[NO + j]     - mean) * rs * gamma[NO + j]     + beta[NO + j];
  const float gv = (combL[2 * NO + j] - mean) * rs * gamma[2 * NO + j] + beta[2 * NO + j];
  const float ov = (combL[3 * NO + j] - mean) * rs * gamma[3 * NO + j] + beta[3 * NO + j];
  const float cold = cst[(size_t)m * NO + j];
  const float cc = sigf(fv) * cold + sigf(iv) * tanhfast(gv);
  const float hh = sigf(ov) * cc;
  cst[(size_t)m * NO + j] = cc;
  out[((size_t)m * NS + t) * NO + j] = hh;
  hf[(size_t)m * NO + j] = hh;
}

// ---------------- launch ----------------

extern "C" void kernel_launch(void* const* d_in, const int* in_sizes, int n_in,
                              void* d_out, int out_size, void* d_ws, size_t ws_size,
                              hipStream_t stream) {
  (void)in_sizes; (void)n_in; (void)out_size;
  const float* x     = (const float*)d_in[0];
  const float* W     = (const float*)d_in[1];
  const float* bias  = (const float*)d_in[2];
  const float* gamma = (const float*)d_in[3];
  const float* beta  = (const float*)d_in[4];
  const float* hx0   = (const float*)d_in[5];
  const float* cx0   = (const float*)d_in[6];
  float* outp = (float*)d_out;

  char* ws = (char*)d_ws;
  size_t off = 0;
  auto alloc = [&](size_t bytes) -> char* {
    off = (off + 255) & ~(size_t)255;
    char* p = ws + off;
    off += bytes;
    return p;
  };
  // small (all tiers)
  float* comb           = (float*)alloc((size_t)NB * NC * 4);            // 512KB
  float* cst            = (float*)alloc((size_t)NB * NO * 4);            // 128KB
  float* hf             = (float*)alloc((size_t)NB * NO * 4);            // 128KB
  __hip_bfloat16* hfrag = (__hip_bfloat16*)alloc((size_t)NB * NO * 2);   // 64KB
  _Float16* combH[2];
  combH[0] = (_Float16*)alloc((size_t)NB * NC * 2);                      // 256KB
  combH[1] = (_Float16*)alloc((size_t)NB * NC * 2);
  _Float16* cH[2];
  cH[0] = (_Float16*)alloc((size_t)NB * NO * 2);                         // 64KB
  cH[1] = (_Float16*)alloc((size_t)NB * NO * 2);
  float* part[2];
  part[0] = (float*)alloc((size_t)NB * 128 * 2 * 4);                     // 32KB
  part[1] = (float*)alloc((size_t)NB * 128 * 2 * 4);
  // mid tier
  __hip_bfloat16* xfrag = (__hip_bfloat16*)alloc((size_t)NB * NS * NI * 2);  // 16.8MB
  __hip_bfloat16* WF    = (__hip_bfloat16*)alloc((size_t)NK * NC * 2);       // 16.8MB
  const size_t off_mid = off;
  // full tier
  float* xw             = (float*)alloc((size_t)NS * NB * NC * 4);       // 134.2MB
  const size_t off_full = off;
  const int tier = (ws_size >= off_full) ? 2 : (ws_size >= off_mid) ? 1 : 0;

  hipLaunchKernelGGL(init_state, dim3((NB * NO) / 256), dim3(256), 0, stream,
                     hx0, cx0, hfrag, cst, hf, cH[0]);
  if (tier == 2) {
    hipLaunchKernelGGL(pack_x, dim3(NS, 32), dim3(128), 0, stream, x, xfrag);
    hipLaunchKernelGGL(pack_wf, dim3(256 * 64), dim3(64), 0, stream, W, WF);
    hipLaunchKernelGGL(precompute_xw, dim3(64, 32), dim3(512), 0, stream,
                       xfrag, WF, bias, xw);
    for (int t = 0; t < NS; ++t) {
      const int pr = (t + 1) & 1, pw = t & 1;
      hipLaunchKernelGGL(fused_step, dim3(256), dim3(512), 0, stream,
                         (const _Float16*)combH[pr], combH[pw],
                         (const _Float16*)cH[pr], cH[pw],
                         (const float*)part[pr], part[pw],
                         (const __hip_bfloat16*)WF, (const float*)xw,
                         gamma, beta, hx0, outp, t);
    }
    hipLaunchKernelGGL(final_update, dim3(NB), dim3(1024), 0, stream,
                       (const _Float16*)combH[1], (const _Float16*)cH[1],
                       (const float*)part[1], gamma, beta, outp);
  } else if (tier == 1) {
    hipLaunchKernelGGL(pack_x, dim3(NS, 32), dim3(128), 0, stream, x, xfrag);
    hipLaunchKernelGGL(pack_wf, dim3(256 * 64), dim3(64), 0, stream, W, WF);
    for (int t = 0; t < NS; ++t) {
      hipLaunchKernelGGL(step_gemm_mfma, dim3(256), dim3(512), 0, stream,
                         xfrag, hfrag, WF, bias, comb, t);
      hipLaunchKernelGGL(step_update_row, dim3(NB), dim3(1024), 0, stream,
                         comb, gamma, beta, cst, outp, hfrag, t);
    }
  } else {
    for (int t = 0; t < NS; ++t) {
      hipLaunchKernelGGL(step_gemm_f32, dim3(256), dim3(256), 0, stream,
                         x, hf, W, bias, comb, t);
      hipLaunchKernelGGL(step_update_row_f32, dim3(NB), dim3(1024), 0, stream,
                         comb, gamma, beta, cst, outp, hf, t);
    }
  }
}